// Round 1
// baseline (822.813 us; speedup 1.0000x reference)
//
#include <hip/hip_runtime.h>
#include <hip/hip_bf16.h>

// Static problem sizes (match reference file)
#define B_   8
#define N_   512
#define K_   16
#define EH_  32       // emb_dim // 2
#define NT_  5        // num edge types
#define E_   32768
#define P_   (B_ * N_ * N_)   // 2,097,152 (b,i,j) pairs

// ---------------------------------------------------------------------------
// Kernel 1: scatter edge types into dense A[B][N][N] (int32), plus diagonal.
// A was zeroed via hipMemsetAsync. Reference does .add (accumulate), so we
// atomicAdd; JAX's gather clamps OOB indices, handled later as min(A, NT-1).
// ---------------------------------------------------------------------------
__global__ __launch_bounds__(256) void scatter_k(const int* __restrict__ ei,
                                                 const int* __restrict__ ea,
                                                 int* __restrict__ A) {
    int t = blockIdx.x * 256 + threadIdx.x;
    if (t < E_) {
        int s = ei[t];          // global src node
        int d = ei[E_ + t];     // global dst node
        int g  = s >> 9;        // graph id (equal-sized graphs of N_=512)
        int ls = s & (N_ - 1);  // local src
        int ld = d & (N_ - 1);  // local dst
        atomicAdd(&A[(g * N_ + ls) * N_ + ld], ea[t] + 1);
    } else {
        int n = t - E_;
        if (n < B_ * N_) {      // self loops: fill value 1 on diagonal
            int g = n >> 9;
            int l = n & (N_ - 1);
            atomicAdd(&A[(g * N_ + l) * N_ + l], 1);
        }
    }
}

// ---------------------------------------------------------------------------
// Kernel 2: fused edge_dense = concat(emb_table[min(A,4)], rwse @ W + b).
// 16 threads per (b,i,j) pair: slots 0..7 write the type half (emb row),
// slots 8..15 compute 4 PE outputs each (W columns held in registers).
// Each thread stores exactly one float4 -> block writes contiguous 4 KB.
// ---------------------------------------------------------------------------
#define PPB 256   // pairs per block (grid = P_/PPB), 16 pairs per inner iter
__global__ __launch_bounds__(256) void fuse_k(const float* __restrict__ rwse,
                                              const float* __restrict__ emb,
                                              const float* __restrict__ W,
                                              const float* __restrict__ bias,
                                              const int* __restrict__ A,
                                              float* __restrict__ out) {
    __shared__ float semb[NT_][EH_];   // 5 x 32
    __shared__ float sW[K_][EH_];      // 16 x 32
    __shared__ float sb[EH_];

    const int tid = threadIdx.x;
    for (int i = tid; i < K_ * EH_; i += 256) sW[i >> 5][i & 31] = W[i];
    if (tid < NT_ * EH_) semb[tid >> 5][tid & 31] = emb[tid];
    if (tid < EH_) sb[tid] = bias[tid];
    __syncthreads();

    const int j = tid & 15;        // slot within pair
    const int c = (j - 8) * 4;     // PE output column base (slots 8..15)

    // Preload W columns + bias for PE slots (fixed per thread for all pairs)
    float4 wc[K_];
    float4 bv = {0.f, 0.f, 0.f, 0.f};
    if (j >= 8) {
        #pragma unroll
        for (int k = 0; k < K_; ++k)
            wc[k] = *(const float4*)&sW[k][c];
        bv = *(const float4*)&sb[c];
    }

    const long base = (long)blockIdx.x * PPB;
    #pragma unroll 1
    for (int it = 0; it < PPB / 16; ++it) {
        const long pair = base + it * 16 + (tid >> 4);
        int a = A[pair];                       // 16 lanes same addr -> 1 req
        a = (a < NT_) ? a : (NT_ - 1);         // JAX clamp-on-gather
        float4 o;
        if (j < 8) {
            o = *(const float4*)&semb[a][j * 4];
        } else {
            const float4* rw = (const float4*)(rwse + pair * K_);
            float r[K_];
            *(float4*)&r[0]  = rw[0];
            *(float4*)&r[4]  = rw[1];
            *(float4*)&r[8]  = rw[2];
            *(float4*)&r[12] = rw[3];
            float4 acc = bv;
            #pragma unroll
            for (int k = 0; k < K_; ++k) {
                acc.x = fmaf(r[k], wc[k].x, acc.x);
                acc.y = fmaf(r[k], wc[k].y, acc.y);
                acc.z = fmaf(r[k], wc[k].z, acc.z);
                acc.w = fmaf(r[k], wc[k].w, acc.w);
            }
            o = acc;
        }
        ((float4*)out)[pair * 16 + j] = o;     // fully coalesced
    }
}

// ---------------------------------------------------------------------------
// Kernel 3: edge_attr_emb[e][c] = emb_table[edge_attr[e]][c]   (E x 32)
// ---------------------------------------------------------------------------
__global__ __launch_bounds__(256) void attr_k(const float* __restrict__ emb,
                                              const int* __restrict__ ea,
                                              float* __restrict__ out2) {
    int t = blockIdx.x * 256 + threadIdx.x;    // t < E_*EH_
    int e = t >> 5, cc = t & 31;
    out2[t] = emb[ea[e] * EH_ + cc];
}

extern "C" void kernel_launch(void* const* d_in, const int* in_sizes, int n_in,
                              void* d_out, int out_size, void* d_ws, size_t ws_size,
                              hipStream_t stream) {
    const float* rwse = (const float*)d_in[0];   // [B*N*N, K]
    const float* emb  = (const float*)d_in[1];   // [NT, EH]
    const float* W    = (const float*)d_in[2];   // [K, EH]
    const float* bias = (const float*)d_in[3];   // [EH]
    const int*   ei   = (const int*)d_in[4];     // [2, E]
    const int*   ea   = (const int*)d_in[5];     // [E]
    // d_in[6] node_batch, d_in[7] B, d_in[8] N_max: structure is static.

    int*   A    = (int*)d_ws;                    // B*N*N int32 = 8 MB scratch
    float* out  = (float*)d_out;                 // edge_dense [B,N,N,64]
    float* out2 = out + (long)P_ * 64;           // edge_attr_emb [E,32]

    hipMemsetAsync(A, 0, (size_t)P_ * sizeof(int), stream);
    scatter_k<<<(E_ + B_ * N_ + 255) / 256, 256, 0, stream>>>(ei, ea, A);
    fuse_k<<<P_ / PPB, 256, 0, stream>>>(rwse, emb, W, bias, A, out);
    attr_k<<<(E_ * EH_) / 256, 256, 0, stream>>>(emb, ea, out2);
}

// Round 3
// 721.648 us; speedup vs baseline: 1.1402x; 1.1402x over previous
//
#include <hip/hip_runtime.h>
#include <hip/hip_bf16.h>

// Static problem sizes (match reference file)
#define B_   8
#define N_   512
#define K_   16
#define EH_  32       // emb_dim // 2
#define NT_  5        // num edge types
#define E_   32768
#define P_   (B_ * N_ * N_)   // 2,097,152 (b,i,j) pairs

typedef __attribute__((ext_vector_type(4))) float f32x4;

// ---------------------------------------------------------------------------
// Kernel 1: (a) scatter edge types into dense A[B][N][N] (+ diagonal), and
// (b) edge_attr_emb = emb_table[edge_attr]  (E x 32, float4 per thread).
// A was zeroed via hipMemsetAsync (stream-ordered before this kernel).
// ---------------------------------------------------------------------------
__global__ __launch_bounds__(256) void prep_k(const int* __restrict__ ei,
                                              const int* __restrict__ ea,
                                              const float* __restrict__ emb,
                                              int* __restrict__ A,
                                              f32x4* __restrict__ out2) {
    int t = blockIdx.x * 256 + threadIdx.x;
    // (b) attr embedding: E_*EH_/4 = 262144 float4 writes, fully coalesced
    if (t < E_ * (EH_ / 4)) {
        int e = t >> 3, c4 = t & 7;
        out2[e * 8 + c4] = ((const f32x4*)emb)[ea[e] * 8 + c4];
    }
    // (a) edge scatter (reference accumulates; clamp happens at gather time)
    if (t < E_) {
        int s = ei[t];          // global src node
        int d = ei[E_ + t];     // global dst node
        int g  = s >> 9;        // graph id (equal graphs of N_=512)
        int ls = s & (N_ - 1);
        int ld = d & (N_ - 1);
        atomicAdd(&A[(g * N_ + ls) * N_ + ld], ea[t] + 1);
    } else if (t - E_ < B_ * N_) {
        int n = t - E_;         // n = g*N_ + l  ->  A[n*N_ + l]
        atomicAdd(&A[n * N_ + (n & (N_ - 1))], 1);  // self-loop fill = 1
    }
}

// ---------------------------------------------------------------------------
// Kernel 2: fused edge_dense = concat(emb_table[min(A,4)], rwse @ W + b).
// 16 threads per (b,i,j) pair: slots 0..7 write the type half (emb row),
// slots 8..15 compute 4 PE outputs each (W columns held in registers).
// Each thread stores exactly one float4 -> block writes contiguous 4 KB/iter.
// Block's 256 A values staged once through LDS (one coalesced load).
// ---------------------------------------------------------------------------
#define PPB 256   // pairs per block (grid = P_/PPB), 16 pairs per inner iter
__global__ __launch_bounds__(256) void fuse_k(const float* __restrict__ rwse,
                                              const float* __restrict__ emb,
                                              const float* __restrict__ W,
                                              const float* __restrict__ bias,
                                              const int* __restrict__ A,
                                              float* __restrict__ out) {
    __shared__ float semb[NT_][EH_];   // 5 x 32
    __shared__ float sW[K_][EH_];      // 16 x 32
    __shared__ float sb[EH_];
    __shared__ int   sA[PPB];

    const int tid = threadIdx.x;
    const long base = (long)blockIdx.x * PPB;

    for (int i = tid; i < K_ * EH_; i += 256) sW[i >> 5][i & 31] = W[i];
    if (tid < NT_ * EH_) semb[tid >> 5][tid & 31] = emb[tid];
    if (tid < EH_) sb[tid] = bias[tid];
    {   // one coalesced load of this block's 256 A entries; clamp here
        int a = A[base + tid];
        sA[tid] = (a < NT_) ? a : (NT_ - 1);   // JAX clamp-on-gather
    }
    __syncthreads();

    const int j = tid & 15;        // slot within pair
    const int c = (j - 8) * 4;     // PE output column base (slots 8..15)

    // W columns + bias in registers for PE slots (fixed for all pairs)
    f32x4 wc[K_];
    f32x4 bv = {0.f, 0.f, 0.f, 0.f};
    if (j >= 8) {
        #pragma unroll
        for (int k = 0; k < K_; ++k)
            wc[k] = *(const f32x4*)&sW[k][c];
        bv = *(const f32x4*)&sb[c];
    }

    f32x4* __restrict__ outv = (f32x4*)out;
    #pragma unroll 2
    for (int it = 0; it < PPB / 16; ++it) {
        const int  lp   = it * 16 + (tid >> 4);   // local pair in block
        const long pair = base + lp;
        f32x4 o;
        if (j < 8) {
            int a = sA[lp];                        // LDS broadcast
            o = *(const f32x4*)&semb[a][j * 4];
        } else {
            const f32x4* rw = (const f32x4*)(rwse + pair * K_);
            f32x4 acc = bv;
            #pragma unroll
            for (int kk = 0; kk < 4; ++kk) {
                f32x4 rv = __builtin_nontemporal_load(&rw[kk]);
                acc.x = fmaf(rv.x, wc[4*kk+0].x, acc.x);
                acc.y = fmaf(rv.x, wc[4*kk+0].y, acc.y);
                acc.z = fmaf(rv.x, wc[4*kk+0].z, acc.z);
                acc.w = fmaf(rv.x, wc[4*kk+0].w, acc.w);
                acc.x = fmaf(rv.y, wc[4*kk+1].x, acc.x);
                acc.y = fmaf(rv.y, wc[4*kk+1].y, acc.y);
                acc.z = fmaf(rv.y, wc[4*kk+1].z, acc.z);
                acc.w = fmaf(rv.y, wc[4*kk+1].w, acc.w);
                acc.x = fmaf(rv.z, wc[4*kk+2].x, acc.x);
                acc.y = fmaf(rv.z, wc[4*kk+2].y, acc.y);
                acc.z = fmaf(rv.z, wc[4*kk+2].z, acc.z);
                acc.w = fmaf(rv.z, wc[4*kk+2].w, acc.w);
                acc.x = fmaf(rv.w, wc[4*kk+3].x, acc.x);
                acc.y = fmaf(rv.w, wc[4*kk+3].y, acc.y);
                acc.z = fmaf(rv.w, wc[4*kk+3].z, acc.z);
                acc.w = fmaf(rv.w, wc[4*kk+3].w, acc.w);
            }
            o = acc;
        }
        // fully coalesced: index = base*16 + it*256 + tid
        __builtin_nontemporal_store(o, &outv[pair * 16 + j]);
    }
}

extern "C" void kernel_launch(void* const* d_in, const int* in_sizes, int n_in,
                              void* d_out, int out_size, void* d_ws, size_t ws_size,
                              hipStream_t stream) {
    const float* rwse = (const float*)d_in[0];   // [B*N*N, K]
    const float* emb  = (const float*)d_in[1];   // [NT, EH]
    const float* W    = (const float*)d_in[2];   // [K, EH]
    const float* bias = (const float*)d_in[3];   // [EH]
    const int*   ei   = (const int*)d_in[4];     // [2, E]
    const int*   ea   = (const int*)d_in[5];     // [E]
    // d_in[6] node_batch, d_in[7] B, d_in[8] N_max: structure is static.

    int*   A    = (int*)d_ws;                    // B*N*N int32 = 8 MB scratch
    float* out  = (float*)d_out;                 // edge_dense [B,N,N,64]
    f32x4* out2 = (f32x4*)(out + (long)P_ * 64); // edge_attr_emb [E,32]

    hipMemsetAsync(A, 0, (size_t)P_ * sizeof(int), stream);
    int prep_threads = E_ * (EH_ / 4);           // covers attr + scatter + diag
    prep_k<<<(prep_threads + 255) / 256, 256, 0, stream>>>(ei, ea, emb, A, out2);
    fuse_k<<<P_ / PPB, 256, 0, stream>>>(rwse, emb, W, bias, A, out);
}

// Round 5
// 700.420 us; speedup vs baseline: 1.1747x; 1.0303x over previous
//
#include <hip/hip_runtime.h>
#include <hip/hip_bf16.h>

// Static problem sizes (match reference file)
#define B_   8
#define N_   512
#define K_   16
#define EH_  32       // emb_dim // 2
#define NT_  5        // num edge types
#define E_   32768
#define P_   (B_ * N_ * N_)   // 2,097,152 (b,i,j) pairs

typedef __attribute__((ext_vector_type(4))) float f32x4;

// ---------------------------------------------------------------------------
// Kernel 1: (a) scatter edge types into dense A[B][N][N] (+ diagonal), and
// (b) edge_attr_emb = emb_table[edge_attr]  (E x 32, float4 per thread).
// A was zeroed via hipMemsetAsync (stream-ordered before this kernel).
// ---------------------------------------------------------------------------
__global__ __launch_bounds__(256) void prep_k(const int* __restrict__ ei,
                                              const int* __restrict__ ea,
                                              const float* __restrict__ emb,
                                              int* __restrict__ A,
                                              f32x4* __restrict__ out2) {
    int t = blockIdx.x * 256 + threadIdx.x;
    // (b) attr embedding: E_*EH_/4 = 262144 float4 writes, fully coalesced
    if (t < E_ * (EH_ / 4)) {
        int e = t >> 3, c4 = t & 7;
        out2[e * 8 + c4] = ((const f32x4*)emb)[ea[e] * 8 + c4];
    }
    // (a) edge scatter (reference accumulates; clamp happens at gather time)
    if (t < E_) {
        int s = ei[t];          // global src node
        int d = ei[E_ + t];     // global dst node
        int g  = s >> 9;        // graph id (equal graphs of N_=512)
        int ls = s & (N_ - 1);
        int ld = d & (N_ - 1);
        atomicAdd(&A[(g * N_ + ls) * N_ + ld], ea[t] + 1);
    } else if (t - E_ < B_ * N_) {
        int n = t - E_;         // n = g*N_ + l  ->  A[n*N_ + l]
        atomicAdd(&A[n * N_ + (n & (N_ - 1))], 1);  // self-loop fill = 1
    }
}

// ---------------------------------------------------------------------------
// Kernel 2: fused edge_dense = concat(emb_table[min(A,4)], rwse @ W + b).
// 16 threads per (b,i,j) pair: slots 0..7 write the type half (emb row),
// slots 8..15 compute 4 PE outputs each (W columns held in registers).
// Each thread stores exactly one float4 -> block writes contiguous 4 KB/iter.
// One-iteration software pipeline: iter it+1's RWSE loads are issued before
// iter it's FMAs so HBM latency hides under compute + store issue.
// ---------------------------------------------------------------------------
#define PPB 256   // pairs per block (grid = P_/PPB), 16 pairs per inner iter
__global__ __launch_bounds__(256) void fuse_k(const float* __restrict__ rwse,
                                              const float* __restrict__ emb,
                                              const float* __restrict__ W,
                                              const float* __restrict__ bias,
                                              const int* __restrict__ A,
                                              float* __restrict__ out) {
    __shared__ float semb[NT_][EH_];   // 5 x 32
    __shared__ float sW[K_][EH_];      // 16 x 32
    __shared__ float sb[EH_];
    __shared__ int   sA[PPB];

    const int tid = threadIdx.x;
    const long base = (long)blockIdx.x * PPB;

    for (int i = tid; i < K_ * EH_; i += 256) sW[i >> 5][i & 31] = W[i];
    if (tid < NT_ * EH_) semb[tid >> 5][tid & 31] = emb[tid];
    if (tid < EH_) sb[tid] = bias[tid];
    {   // one coalesced load of this block's 256 A entries; clamp here
        int a = A[base + tid];
        sA[tid] = (a < NT_) ? a : (NT_ - 1);   // JAX clamp-on-gather
    }
    __syncthreads();

    const int  j  = tid & 15;       // slot within pair
    const bool pe = (j >= 8);
    const int  c  = (j - 8) * 4;    // PE output column base (slots 8..15)

    // W columns + bias in registers for PE slots (fixed for all pairs)
    f32x4 wc[K_];
    f32x4 bv = {0.f, 0.f, 0.f, 0.f};
    if (pe) {
        #pragma unroll
        for (int k = 0; k < K_; ++k)
            wc[k] = *(const f32x4*)&sW[k][c];
        bv = *(const f32x4*)&sb[c];
    }

    f32x4* __restrict__ outv = (f32x4*)out;
    const long p0 = base + (tid >> 4);

    // prologue: issue iter-0 loads
    f32x4 rv0, rv1, rv2, rv3;
    if (pe) {
        const f32x4* rw = (const f32x4*)(rwse + p0 * K_);
        rv0 = __builtin_nontemporal_load(&rw[0]);
        rv1 = __builtin_nontemporal_load(&rw[1]);
        rv2 = __builtin_nontemporal_load(&rw[2]);
        rv3 = __builtin_nontemporal_load(&rw[3]);
    }

    #pragma unroll 2
    for (int it = 0; it < PPB / 16; ++it) {
        const int  lp   = it * 16 + (tid >> 4);
        const long pair = base + lp;

        // issue next iteration's loads BEFORE this iteration's FMAs
        f32x4 nv0, nv1, nv2, nv3;
        if (pe && it + 1 < PPB / 16) {
            const f32x4* rw = (const f32x4*)(rwse + (pair + 16) * K_);
            nv0 = __builtin_nontemporal_load(&rw[0]);
            nv1 = __builtin_nontemporal_load(&rw[1]);
            nv2 = __builtin_nontemporal_load(&rw[2]);
            nv3 = __builtin_nontemporal_load(&rw[3]);
        }

        f32x4 o;
        if (!pe) {
            int a = sA[lp];                        // LDS broadcast
            o = *(const f32x4*)&semb[a][j * 4];
        } else {
            f32x4 acc = bv;
            #pragma unroll
            for (int q = 0; q < 4; ++q) {
                float r = (q == 0) ? rv0.x : (q == 1) ? rv1.x : (q == 2) ? rv2.x : rv3.x;
                float s = (q == 0) ? rv0.y : (q == 1) ? rv1.y : (q == 2) ? rv2.y : rv3.y;
                float u = (q == 0) ? rv0.z : (q == 1) ? rv1.z : (q == 2) ? rv2.z : rv3.z;
                float v = (q == 0) ? rv0.w : (q == 1) ? rv1.w : (q == 2) ? rv2.w : rv3.w;
                acc.x = fmaf(r, wc[4*q+0].x, acc.x);
                acc.y = fmaf(r, wc[4*q+0].y, acc.y);
                acc.z = fmaf(r, wc[4*q+0].z, acc.z);
                acc.w = fmaf(r, wc[4*q+0].w, acc.w);
                acc.x = fmaf(s, wc[4*q+1].x, acc.x);
                acc.y = fmaf(s, wc[4*q+1].y, acc.y);
                acc.z = fmaf(s, wc[4*q+1].z, acc.z);
                acc.w = fmaf(s, wc[4*q+1].w, acc.w);
                acc.x = fmaf(u, wc[4*q+2].x, acc.x);
                acc.y = fmaf(u, wc[4*q+2].y, acc.y);
                acc.z = fmaf(u, wc[4*q+2].z, acc.z);
                acc.w = fmaf(u, wc[4*q+2].w, acc.w);
                acc.x = fmaf(v, wc[4*q+3].x, acc.x);
                acc.y = fmaf(v, wc[4*q+3].y, acc.y);
                acc.z = fmaf(v, wc[4*q+3].z, acc.z);
                acc.w = fmaf(v, wc[4*q+3].w, acc.w);
            }
            o = acc;
        }
        // fully coalesced: index = base*16 + it*256 + tid
        __builtin_nontemporal_store(o, &outv[pair * 16 + j]);

        rv0 = nv0; rv1 = nv1; rv2 = nv2; rv3 = nv3;
    }
}

extern "C" void kernel_launch(void* const* d_in, const int* in_sizes, int n_in,
                              void* d_out, int out_size, void* d_ws, size_t ws_size,
                              hipStream_t stream) {
    const float* rwse = (const float*)d_in[0];   // [B*N*N, K]
    const float* emb  = (const float*)d_in[1];   // [NT, EH]
    const float* W    = (const float*)d_in[2];   // [K, EH]
    const float* bias = (const float*)d_in[3];   // [EH]
    const int*   ei   = (const int*)d_in[4];     // [2, E]
    const int*   ea   = (const int*)d_in[5];     // [E]
    // d_in[6] node_batch, d_in[7] B, d_in[8] N_max: structure is static.

    int*   A    = (int*)d_ws;                    // B*N*N int32 = 8 MB scratch
    float* out  = (float*)d_out;                 // edge_dense [B,N,N,64]
    f32x4* out2 = (f32x4*)(out + (long)P_ * 64); // edge_attr_emb [E,32]

    hipMemsetAsync(A, 0, (size_t)P_ * sizeof(int), stream);
    int prep_threads = E_ * (EH_ / 4);           // covers attr + scatter + diag
    prep_k<<<(prep_threads + 255) / 256, 256, 0, stream>>>(ei, ea, emb, A, out2);
    fuse_k<<<P_ / PPB, 256, 0, stream>>>(rwse, emb, W, bias, A, out);
}